// Round 14
// baseline (1433.087 us; speedup 1.0000x reference)
//
#include <hip/hip_runtime.h>
#include <hip/hip_bf16.h>
#include <cstdint>

typedef unsigned short u16;
typedef uint32_t u32;
typedef __bf16 bf16x8 __attribute__((ext_vector_type(8)));
typedef float f32x4 __attribute__((ext_vector_type(4)));
typedef u16 u16x4 __attribute__((ext_vector_type(4)));
typedef u16 u16x8 __attribute__((ext_vector_type(8)));

#define DD 1024
#define DFF 4096
#define NTOK 2048
#define SEQ 512

__device__ __forceinline__ float bf2f(u16 u) { return __uint_as_float(((u32)u) << 16); }
__device__ __forceinline__ u16 f2bf(float f) {
  __hip_bfloat16 h = __float2bfloat16(f);
  return *reinterpret_cast<u16*>(&h);
}
__device__ __forceinline__ void gload16(const void* g, void* l) {
  __builtin_amdgcn_global_load_lds((const __attribute__((address_space(1))) u32*)g,
                                   (__attribute__((address_space(3))) u32*)l, 16, 0, 0);
}

// -------- embedding + positional (f32 in, f32 + bf16 out); also zeroes BN counter --------
__global__ __launch_bounds__(256) void embed_k(const int* __restrict__ seq,
    const float* __restrict__ pes, const float* __restrict__ emb,
    float* __restrict__ x, u16* __restrict__ xb, u32* __restrict__ cnt) {
  if (blockIdx.x == 0 && threadIdx.x == 0) *cnt = 0;
  int t = blockIdx.x;
  int s = t & (SEQ - 1);
  int tok = seq[t];
  int c = threadIdx.x * 4;
  float4 e = *(const float4*)(emb + (size_t)tok * DD + c);
  float4 p = *(const float4*)(pes + (size_t)s * DD + c);
  float o0 = e.x + p.x, o1 = e.y + p.y, o2 = e.z + p.z, o3 = e.w + p.w;
  size_t i = (size_t)t * DD + c;
  *(float4*)(x + i) = make_float4(o0, o1, o2, o3);
  u16x4 ob; ob[0] = f2bf(o0); ob[1] = f2bf(o1); ob[2] = f2bf(o2); ob[3] = f2bf(o3);
  *(u16x4*)(xb + i) = ob;
}

// -- 64x64-tile transpose + f32->bf16: dst[C][R] = bf16(src[R][C]^T) --
__device__ __forceinline__ void transp_tile(const float* src, u16* dst, int R, int C,
                                            int tr, int tc, int tid) {
  __shared__ float tbuf[64 * 65];
#pragma unroll
  for (int i = 0; i < 4; ++i) {
    int f = i * 256 + tid;
    int r = f >> 4, c4 = (f & 15) * 4;
    float4 a = *(const float4*)(src + (size_t)(tr + r) * C + tc + c4);
    tbuf[r * 65 + c4 + 0] = a.x;
    tbuf[r * 65 + c4 + 1] = a.y;
    tbuf[r * 65 + c4 + 2] = a.z;
    tbuf[r * 65 + c4 + 3] = a.w;
  }
  __syncthreads();
#pragma unroll
  for (int i = 0; i < 2; ++i) {
    int g = i * 256 + tid;
    int c = g >> 3, rc = g & 7;
    u16x8 v;
#pragma unroll
    for (int j = 0; j < 8; ++j) v[j] = f2bf(tbuf[(rc * 8 + j) * 65 + c]);
    *(u16x8*)(dst + (size_t)(tc + c) * R + tr + rc * 8) = v;
  }
}

// ---- square-weight transposes (Wq,Wk,Wv,Wo x 6 layers), 6144 blocks ----
__global__ __launch_bounds__(256) void transp_sq(
    const float* __restrict__ Wq, const float* __restrict__ Wk,
    const float* __restrict__ Wv, const float* __restrict__ Wo,
    u16* __restrict__ wt) {
  int bid = blockIdx.x;
  int l = bid >> 10, z = bid & 1023;
  int m = z >> 8;
  const float* w = (m == 0) ? Wq : (m == 1) ? Wk : (m == 2) ? Wv : Wo;
  const float* src = w + (size_t)l * DD * DD;
  u16* dst = wt + (size_t)l * 12582912 + (size_t)m * DD * DD;
  int t2 = z & 255;
  transp_tile(src, dst, 1024, 1024, (t2 >> 4) * 64, (t2 & 15) * 64, threadIdx.x);
}

// ---- FFN-weight transposes (W1,W2 x 6 layers), 12288 blocks ----
__global__ __launch_bounds__(256) void transp_ffn(
    const float* __restrict__ W1, const float* __restrict__ W2,
    u16* __restrict__ wt) {
  int bid = blockIdx.x;
  int l = bid >> 11, z = bid & 2047;
  u16* base = wt + (size_t)l * 12582912;
  if (z < 1024) {
    const float* src = W1 + (size_t)l * DD * DFF;
    u16* dst = base + 4 * DD * DD;
    transp_tile(src, dst, 1024, 4096, (z >> 6) * 64, (z & 63) * 64, threadIdx.x);
  } else {
    int t2 = z - 1024;
    const float* src = W2 + (size_t)l * DFF * DD;
    u16* dst = base + 4 * DD * DD + DD * DFF;
    transp_tile(src, dst, 4096, 1024, (t2 >> 4) * 64, (t2 & 15) * 64, threadIdx.x);
  }
}

// ================= 128x128 2-phase GEMM core (proven) =================
#define STAGEAB(buf, kk0)                                                       \
  _Pragma("unroll")                                                             \
  for (int i_ = 0; i_ < 4; ++i_) {                                              \
    int g_ = i_ * 256 + tid;                                                    \
    int r_ = g_ >> 3, b_ = g_ & 7;                                              \
    int bs_ = b_ ^ (r_ & 7);                                                    \
    gload16(Ab + (size_t)r_ * K + (kk0) + bs_ * 8,                              \
            (char*)Als + (buf) * 16384 + g_ * 16);                              \
    gload16(Bb + (size_t)r_ * K + (kk0) + bs_ * 8,                              \
            (char*)Bls + (buf) * 16384 + g_ * 16);                              \
  }

#define FRAGS_MFMA(Ac, Bc)                                                      \
  _Pragma("unroll")                                                             \
  for (int kk = 0; kk < 2; ++kk) {                                              \
    bf16x8 av[4], bv[4];                                                        \
    _Pragma("unroll")                                                           \
    for (int m = 0; m < 4; ++m) {                                               \
      int r = wr + m * 16 + lr;                                                 \
      av[m] = *(const bf16x8*)((Ac) + r * 64 + (((kk * 4 + lg) ^ (r & 7)) * 8));\
    }                                                                           \
    _Pragma("unroll")                                                           \
    for (int n = 0; n < 4; ++n) {                                               \
      int r = wc + n * 16 + lr;                                                 \
      bv[n] = *(const bf16x8*)((Bc) + r * 64 + (((kk * 4 + lg) ^ (r & 7)) * 8));\
    }                                                                           \
    _Pragma("unroll")                                                           \
    for (int m = 0; m < 4; ++m)                                                 \
      _Pragma("unroll")                                                         \
      for (int n = 0; n < 4; ++n)                                               \
        acc[m][n] = __builtin_amdgcn_mfma_f32_16x16x32_bf16(av[m], bv[n],       \
                                                            acc[m][n], 0, 0, 0);\
  }

#define KLOOP(kb_, ke_)                                                         \
  STAGEAB(0, (kb_));                                                            \
  STAGEAB(1, (kb_) + 64);                                                       \
  {                                                                             \
    int cur = 0;                                                                \
    for (int k0 = (kb_); k0 < (ke_); k0 += 64) {                                \
      if (k0 + 64 < (ke_)) asm volatile("s_waitcnt vmcnt(8)" ::: "memory");     \
      else                 asm volatile("s_waitcnt vmcnt(0)" ::: "memory");     \
      __builtin_amdgcn_s_barrier();                                             \
      asm volatile("" ::: "memory");                                            \
      const u16* Ac = Als + cur * 8192;                                         \
      const u16* Bc = Bls + cur * 8192;                                         \
      FRAGS_MFMA(Ac, Bc);                                                       \
      __builtin_amdgcn_s_barrier();                                             \
      asm volatile("" ::: "memory");                                            \
      if (k0 + 128 < (ke_)) { STAGEAB(cur, k0 + 128); }                         \
      cur ^= 1;                                                                 \
    }                                                                           \
  }

// 1-D grid, XCD-pinned. VT: z==2 output written V-transposed into vtout[bh][hd][s].
template<int RELU, int BNL, int VT>
__global__ __launch_bounds__(256) void gemm_k(
    const u16* __restrict__ A,
    const u16* __restrict__ B0, const u16* __restrict__ B1, const u16* __restrict__ B2,
    const float* __restrict__ bi0, const float* __restrict__ bi1, const float* __restrict__ bi2,
    u16* __restrict__ outb, u16* __restrict__ vtout, int M, int N, int K) {
  int bid = blockIdx.x;
  int bn = bid & ((1 << BNL) - 1);
  int bm = (bid >> BNL) & 15;
  int z = bid >> (BNL + 4);
  const u16* Bt = (z == 0) ? B0 : (z == 1) ? B1 : B2;
  const float* bias = (z == 0) ? bi0 : (z == 1) ? bi1 : bi2;
  __shared__ __attribute__((aligned(16))) u16 Als[2 * 8192];
  __shared__ __attribute__((aligned(16))) u16 Bls[2 * 8192];
  int tid = threadIdx.x;
  int wave = tid >> 6, lane = tid & 63;
  int lr = lane & 15, lg = lane >> 4;
  int wr = (wave >> 1) * 64, wc = (wave & 1) * 64;
  int bm0 = bm * 128, bn0 = bn * 128;
  const u16* Ab = A + (size_t)bm0 * K;
  const u16* Bb = Bt + (size_t)bn0 * K;
  f32x4 acc[4][4] = {};
  KLOOP(0, K);
  size_t zoff = (size_t)z * M * N;
  float bb[4];
#pragma unroll
  for (int n = 0; n < 4; ++n) bb[n] = bias[bn0 + wc + n * 16 + lr];
#pragma unroll
  for (int m = 0; m < 4; ++m) {
    int row0 = bm0 + wr + m * 16 + lg * 4;
#pragma unroll
    for (int n = 0; n < 4; ++n) {
      int col = bn0 + wc + n * 16 + lr;
      if (VT && z == 2) {
        u16x4 ov;
#pragma unroll
        for (int j = 0; j < 4; ++j) ov[j] = f2bf(acc[m][n][j] + bb[n]);
        int b = row0 >> 9, s0 = row0 & 511;
        int h = col >> 6, hd = col & 63;
        *(u16x4*)(vtout + ((size_t)(((b << 4) + h) << 6) + hd) * 512 + s0) = ov;
      } else {
#pragma unroll
        for (int j = 0; j < 4; ++j) {
          float v = acc[m][n][j] + bb[n];
          if (RELU) v = fmaxf(v, 0.f);
          outb[zoff + (size_t)(row0 + j) * N + col] = f2bf(v);
        }
      }
    }
  }
}

// ---- split-K GEMM, de-atomized: each z writes its own bf16 partial buffer ----
__global__ __launch_bounds__(256) void gemm_splitp(
    const u16* __restrict__ A, const u16* __restrict__ Bt,
    u16* __restrict__ out, int M, int N, int K, int KS) {
  int bid = blockIdx.x;
  int bn = bid & 7;
  int bm = (bid >> 3) & 15;
  int zz = bid >> 7;
  __shared__ __attribute__((aligned(16))) u16 Als[2 * 8192];
  __shared__ __attribute__((aligned(16))) u16 Bls[2 * 8192];
  int tid = threadIdx.x;
  int wave = tid >> 6, lane = tid & 63;
  int lr = lane & 15, lg = lane >> 4;
  int wr = (wave >> 1) * 64, wc = (wave & 1) * 64;
  int bm0 = bm * 128, bn0 = bn * 128;
  int kb = zz * KS, ke = kb + KS;
  const u16* Ab = A + (size_t)bm0 * K;
  const u16* Bb = Bt + (size_t)bn0 * K;
  f32x4 acc[4][4] = {};
  KLOOP(kb, ke);
  u16* op = out + (size_t)zz * M * N;
#pragma unroll
  for (int m = 0; m < 4; ++m) {
    int row0 = bm0 + wr + m * 16 + lg * 4;
#pragma unroll
    for (int n = 0; n < 4; ++n) {
      int col = bn0 + wc + n * 16 + lr;
#pragma unroll
      for (int j = 0; j < 4; ++j)
        op[(size_t)(row0 + j) * N + col] = f2bf(acc[m][n][j]);
    }
  }
}

// ------- attention: one (b,h), 16 q-rows per block; 1-D XCD-pinned grid -------
__global__ __launch_bounds__(256) void attn_k(const u16* __restrict__ q,
    const u16* __restrict__ k, const u16* __restrict__ vt, u16* __restrict__ o) {
  int bid = blockIdx.x;
  int bh = ((bid & 7) << 3) | ((bid >> 3) & 7);
  int q0 = (bid >> 6) * 16;
  int b = bh >> 4, h = bh & 15;
  int tid = threadIdx.x;
  int wave = tid >> 6, lane = tid & 63;
  int lr = lane & 15, lg = lane >> 4;
  __shared__ __attribute__((aligned(16))) float sc[16 * 512];
  __shared__ __attribute__((aligned(16))) u16 Qs[16 * 64];
  __shared__ __attribute__((aligned(16))) u16 Ks[64 * 64];
  __shared__ __attribute__((aligned(16))) u16 Vs[64 * 64];
  __shared__ float red[16][17];
  __shared__ float rscale[16];
  if (tid < 128) {
    int r = tid >> 3, c = tid & 7;
    u16x8 t = *(const u16x8*)(q + (size_t)(b * SEQ + q0 + r) * DD + h * 64 + c * 8);
    *(u16x8*)(Qs + r * 64 + ((c ^ (r & 7)) * 8)) = t;
  }
  __syncthreads();
  bf16x8 qa[2];
#pragma unroll
  for (int kk = 0; kk < 2; ++kk)
    qa[kk] = *(const bf16x8*)(Qs + lr * 64 + (((kk * 4 + lg) ^ (lr & 7)) * 8));
  for (int kt = 0; kt < 8; ++kt) {
    const u16* kb0 = k + (size_t)(b * SEQ + kt * 64) * DD + h * 64;
#pragma unroll
    for (int i = 0; i < 2; ++i) {
      int g = i * 256 + tid;
      int r = g >> 3, c = g & 7;
      u16x8 t = *(const u16x8*)(kb0 + (size_t)r * DD + c * 8);
      *(u16x8*)(Ks + r * 64 + ((c ^ (r & 7)) * 8)) = t;
    }
    __syncthreads();
    f32x4 sacc = {};
#pragma unroll
    for (int kk = 0; kk < 2; ++kk) {
      int rr = wave * 16 + lr;
      bf16x8 kb = *(const bf16x8*)(Ks + rr * 64 + (((kk * 4 + lg) ^ (rr & 7)) * 8));
      sacc = __builtin_amdgcn_mfma_f32_16x16x32_bf16(qa[kk], kb, sacc, 0, 0, 0);
    }
#pragma unroll
    for (int j = 0; j < 4; ++j) {
      int row = lg * 4 + j;
      int col = kt * 64 + wave * 16 + lr;
      sc[row * 512 + (col ^ row)] = sacc[j] * 0.125f;
    }
    __syncthreads();
  }
  int r = tid & 15, ch = tid >> 4;
  float vr[32];
  float pmax = -3.0e38f;
#pragma unroll
  for (int i = 0; i < 32; ++i) {
    int c = ch * 32 + i;
    float xv = sc[r * 512 + (c ^ r)];
    vr[i] = xv;
    pmax = fmaxf(pmax, xv);
  }
  red[r][ch] = pmax;
  __syncthreads();
  float m = -3.0e38f;
#pragma unroll
  for (int i = 0; i < 16; ++i) m = fmaxf(m, red[r][i]);
  __syncthreads();
  float psum = 0.f;
#pragma unroll
  for (int i = 0; i < 32; ++i) {
    float e = __expf(vr[i] - m);
    vr[i] = e;
    psum += e;
  }
  red[r][ch] = psum;
  __syncthreads();
  float l = 0.f;
#pragma unroll
  for (int i = 0; i < 16; ++i) l += red[r][i];
  if (ch == 0) rscale[r] = 1.0f / l;
  u16* P = (u16*)sc;
#pragma unroll
  for (int i = 0; i < 32; ++i) {
    int c = ch * 32 + i;
    P[r * 512 + (((c >> 3) ^ (r & 7)) * 8) + (c & 7)] = f2bf(vr[i]);
  }
  f32x4 oacc = {};
  for (int kt = 0; kt < 8; ++kt) {
    __syncthreads();
    const u16* vb0 = vt + (size_t)bh * 64 * SEQ + kt * 64;
#pragma unroll
    for (int i = 0; i < 2; ++i) {
      int g = i * 256 + tid;
      int rr = g >> 3, c = g & 7;
      u16x8 t = *(const u16x8*)(vb0 + (size_t)rr * SEQ + c * 8);
      *(u16x8*)(Vs + rr * 64 + ((c ^ (rr & 7)) * 8)) = t;
    }
    __syncthreads();
#pragma unroll
    for (int kk = 0; kk < 2; ++kk) {
      int cb = kt * 8 + kk * 4 + lg;
      bf16x8 pa = *(const bf16x8*)(P + lr * 512 + ((cb ^ (lr & 7)) * 8));
      int rr = wave * 16 + lr;
      bf16x8 vb = *(const bf16x8*)(Vs + rr * 64 + (((kk * 4 + lg) ^ (rr & 7)) * 8));
      oacc = __builtin_amdgcn_mfma_f32_16x16x32_bf16(pa, vb, oacc, 0, 0, 0);
    }
  }
  __syncthreads();
  float* Of = sc;
#pragma unroll
  for (int j = 0; j < 4; ++j)
    Of[(lg * 4 + j) * 68 + wave * 16 + lr] = oacc[j] * rscale[lg * 4 + j];
  __syncthreads();
  {
    int rr = tid >> 4, c0 = (tid & 15) * 4;
    u16x4 ov;
#pragma unroll
    for (int j = 0; j < 4; ++j) ov[j] = f2bf(Of[rr * 68 + c0 + j]);
    *(u16x4*)(o + (size_t)(b * SEQ + q0 + rr) * DD + h * 64 + c0) = ov;
  }
}

// ---- BN stats (fused reduce): v = sum(4 bf16 partials) + bias + resid;
// materialize v into y; per-rowgroup partial stats; last block reduces -> SS.
__global__ __launch_bounds__(256) void bn_stats_f(const u16* __restrict__ parts,
    const float* __restrict__ bias, const float* __restrict__ resid,
    float* __restrict__ y, float* __restrict__ part,
    const float* __restrict__ g, const float* __restrict__ be,
    float* __restrict__ ss, u32* __restrict__ cnt) {
  int c = blockIdx.x * 256 + threadIdx.x;
  int r0 = blockIdx.y * 32;
  float b = bias[c];
  const u16* p0 = parts;
  const u16* p1 = parts + (size_t)NTOK * DD;
  const u16* p2 = parts + (size_t)2 * NTOK * DD;
  const u16* p3 = parts + (size_t)3 * NTOK * DD;
  float s = 0.f, s2 = 0.f;
  for (int r = 0; r < 32; ++r) {
    size_t idx = (size_t)(r0 + r) * DD + c;
    float v = bf2f(p0[idx]) + bf2f(p1[idx]) + bf2f(p2[idx]) + bf2f(p3[idx])
              + b + resid[idx];
    y[idx] = v;
    s += v; s2 += v * v;
  }
  size_t idx = ((size_t)blockIdx.y * DD + c) * 2;
  part[idx] = s; part[idx + 1] = s2;
  // last-block reduce (256 blocks total)
  __threadfence();
  __shared__ u32 lastflag;
  if (threadIdx.x == 0) lastflag = (atomicAdd(cnt, 1) == 255) ? 1u : 0u;
  __syncthreads();
  if (lastflag) {
    __threadfence();
    int tid = threadIdx.x;
#pragma unroll
    for (int cc = 0; cc < 4; ++cc) {
      int ch = cc * 256 + tid;
      float rs = 0.f, rs2 = 0.f;
      for (int i = 0; i < 64; ++i) {
        rs += part[((size_t)i * DD + ch) * 2];
        rs2 += part[((size_t)i * DD + ch) * 2 + 1];
      }
      float mean = rs * (1.f / 2048.f);
      float var = rs2 * (1.f / 2048.f) - mean * mean;
      float rsq = rsqrtf(var + 1e-3f);
      float sca = g[ch] * rsq;
      ss[ch * 2] = sca;
      ss[ch * 2 + 1] = be[ch] - mean * sca;
    }
    __syncthreads();
    if (tid == 0) *cnt = 0;
  }
}

// bn apply: pure scale pass over materialized v; writes xout(f32) + xb(bf16)
__global__ __launch_bounds__(256) void bn_apply_k(const float* __restrict__ y,
    const float* __restrict__ ss, float* __restrict__ xout, u16* __restrict__ xb) {
  size_t i = ((size_t)blockIdx.x * 256 + threadIdx.x) * 4;
  int c = (int)(i & (DD - 1));
  float4 v = *(const float4*)(y + i);
  float o0 = v.x * ss[c * 2] + ss[c * 2 + 1];
  float o1 = v.y * ss[(c + 1) * 2] + ss[(c + 1) * 2 + 1];
  float o2 = v.z * ss[(c + 2) * 2] + ss[(c + 2) * 2 + 1];
  float o3 = v.w * ss[(c + 3) * 2] + ss[(c + 3) * 2 + 1];
  *(float4*)(xout + i) = make_float4(o0, o1, o2, o3);
  u16x4 ob; ob[0] = f2bf(o0); ob[1] = f2bf(o1); ob[2] = f2bf(o2); ob[3] = f2bf(o3);
  *(u16x4*)(xb + i) = ob;
}

// ---------------- host ----------------
extern "C" void kernel_launch(void* const* d_in, const int* in_sizes, int n_in,
                              void* d_out, int out_size, void* d_ws, size_t ws_size,
                              hipStream_t stream) {
  const int* seq = (const int*)d_in[0];
  const float* pes = (const float*)d_in[1];
  const float* emb = (const float*)d_in[2];
  const float* Wq = (const float*)d_in[3];
  const float* bq = (const float*)d_in[4];
  const float* Wk = (const float*)d_in[5];
  const float* bk = (const float*)d_in[6];
  const float* Wv = (const float*)d_in[7];
  const float* bv = (const float*)d_in[8];
  const float* Wo = (const float*)d_in[9];
  const float* bo = (const float*)d_in[10];
  const float* W1 = (const float*)d_in[11];
  const float* b1 = (const float*)d_in[12];
  const float* W2 = (const float*)d_in[13];
  const float* b2 = (const float*)d_in[14];
  const float* g1 = (const float*)d_in[15];
  const float* be1 = (const float*)d_in[16];
  const float* g2 = (const float*)d_in[17];
  const float* be2 = (const float*)d_in[18];
  (void)in_sizes; (void)n_in; (void)out_size;

  if (ws_size < (size_t)224 * 1048576) return;

  char* ws = (char*)d_ws;
  const size_t MB = 1048576;
  u16* WT = (u16*)(ws);                      // 0..144 MB transposed bf16 weights
  float* XF = (float*)(ws + 144 * MB);       // 8 MB fp32 residual
  u16* XB = (u16*)(ws + 152 * MB);           // 4 MB bf16 x
  float* YF = (float*)(ws + 156 * MB);       // 8 MB fp32 materialized v
  u16* Qb = (u16*)(ws + 164 * MB);           // Q 164..168, K 168..172
  u16* VT = (u16*)(ws + 176 * MB);           // 4 MB
  u16* AT = (u16*)(ws + 180 * MB);           // 4 MB
  u16* HB = (u16*)(ws + 184 * MB);           // 16 MB bf16 hidden
  float* BP = (float*)(ws + 200 * MB);       // 512 KB partial stats
  float* SS = (float*)(ws + 201 * MB);       // 8 KB scale/shift
  u32* CNT = (u32*)(ws + 202 * MB);          // 4 B last-block counter
  u16* YP = (u16*)(ws + 204 * MB);           // 16 MB: 4x bf16 split-K partials

  transp_sq<<<6144, 256, 0, stream>>>(Wq, Wk, Wv, Wo, WT);
  transp_ffn<<<12288, 256, 0, stream>>>(W1, W2, WT);
  embed_k<<<NTOK, 256, 0, stream>>>(seq, pes, emb, XF, XB, CNT);
  for (int l = 0; l < 6; ++l) {
    u16* wl = WT + (size_t)l * 12582912;
    u16* wqT = wl;
    u16* wkT = wl + 1048576;
    u16* wvT = wl + 2097152;
    u16* woT = wl + 3145728;
    u16* w1T = wl + 4194304;
    u16* w2T = wl + 8388608;
    // QKV: 1-D grid 8bn x 16bm x 3z, XCD-pinned; z==2 (V) written transposed to VT
    gemm_k<0, 3, 1><<<384, 256, 0, stream>>>(XB, wqT, wkT, wvT,
        bq + l * DD, bk + l * DD, bv + l * DD, Qb, VT, NTOK, DD, DD);
    attn_k<<<2048, 256, 0, stream>>>(Qb, Qb + (size_t)NTOK * DD, VT, AT);
    // attn-out: split-K=4 bf16 partial buffers (no atomics)
    gemm_splitp<<<512, 256, 0, stream>>>(AT, woT, YP, NTOK, DD, DD, DD / 4);
    bn_stats_f<<<dim3(4, 64), 256, 0, stream>>>(YP, bo + l * DD, XF, YF, BP,
        g1 + l * DD, be1 + l * DD, SS, CNT);
    bn_apply_k<<<NTOK, 256, 0, stream>>>(YF, SS, XF, XB);
    // FFN1: 1-D grid 32bn x 16bm, XCD-pinned
    gemm_k<1, 5, 0><<<512, 256, 0, stream>>>(XB, w1T, w1T, w1T,
        b1 + l * DFF, b1 + l * DFF, b1 + l * DFF, HB, nullptr, NTOK, DFF, DD);
    // FFN2: split-K=4 bf16 partial buffers (no atomics)
    gemm_splitp<<<512, 256, 0, stream>>>(HB, w2T, YP, NTOK, DD, DFF, DFF / 4);
    bn_stats_f<<<dim3(4, 64), 256, 0, stream>>>(YP, b2 + l * DD, XF, YF, BP,
        g2 + l * DD, be2 + l * DD, SS, CNT);
    float* xfo = (l == 5) ? (float*)d_out : XF;
    bn_apply_k<<<NTOK, 256, 0, stream>>>(YF, SS, xfo, XB);
  }
}

// Round 15
// 1016.364 us; speedup vs baseline: 1.4100x; 1.4100x over previous
//
#include <hip/hip_runtime.h>
#include <hip/hip_bf16.h>
#include <cstdint>

typedef unsigned short u16;
typedef uint32_t u32;
typedef __bf16 bf16x8 __attribute__((ext_vector_type(8)));
typedef float f32x4 __attribute__((ext_vector_type(4)));
typedef u16 u16x4 __attribute__((ext_vector_type(4)));
typedef u16 u16x8 __attribute__((ext_vector_type(8)));

#define DD 1024
#define DFF 4096
#define NTOK 2048
#define SEQ 512

__device__ __forceinline__ float bf2f(u16 u) { return __uint_as_float(((u32)u) << 16); }
__device__ __forceinline__ u16 f2bf(float f) {
  __hip_bfloat16 h = __float2bfloat16(f);
  return *reinterpret_cast<u16*>(&h);
}
__device__ __forceinline__ void gload16(const void* g, void* l) {
  __builtin_amdgcn_global_load_lds((const __attribute__((address_space(1))) u32*)g,
                                   (__attribute__((address_space(3))) u32*)l, 16, 0, 0);
}

// -------- embedding + positional (f32 in, f32 + bf16 out) --------
__global__ __launch_bounds__(256) void embed_k(const int* __restrict__ seq,
    const float* __restrict__ pes, const float* __restrict__ emb,
    float* __restrict__ x, u16* __restrict__ xb) {
  int t = blockIdx.x;
  int s = t & (SEQ - 1);
  int tok = seq[t];
  int c = threadIdx.x * 4;
  float4 e = *(const float4*)(emb + (size_t)tok * DD + c);
  float4 p = *(const float4*)(pes + (size_t)s * DD + c);
  float o0 = e.x + p.x, o1 = e.y + p.y, o2 = e.z + p.z, o3 = e.w + p.w;
  size_t i = (size_t)t * DD + c;
  *(float4*)(x + i) = make_float4(o0, o1, o2, o3);
  u16x4 ob; ob[0] = f2bf(o0); ob[1] = f2bf(o1); ob[2] = f2bf(o2); ob[3] = f2bf(o3);
  *(u16x4*)(xb + i) = ob;
}

// -- 64x64-tile transpose + f32->bf16: dst[C][R] = bf16(src[R][C]^T) --
__device__ __forceinline__ void transp_tile(const float* src, u16* dst, int R, int C,
                                            int tr, int tc, int tid) {
  __shared__ float tbuf[64 * 65];
#pragma unroll
  for (int i = 0; i < 4; ++i) {
    int f = i * 256 + tid;
    int r = f >> 4, c4 = (f & 15) * 4;
    float4 a = *(const float4*)(src + (size_t)(tr + r) * C + tc + c4);
    tbuf[r * 65 + c4 + 0] = a.x;
    tbuf[r * 65 + c4 + 1] = a.y;
    tbuf[r * 65 + c4 + 2] = a.z;
    tbuf[r * 65 + c4 + 3] = a.w;
  }
  __syncthreads();
#pragma unroll
  for (int i = 0; i < 2; ++i) {
    int g = i * 256 + tid;
    int c = g >> 3, rc = g & 7;
    u16x8 v;
#pragma unroll
    for (int j = 0; j < 8; ++j) v[j] = f2bf(tbuf[(rc * 8 + j) * 65 + c]);
    *(u16x8*)(dst + (size_t)(tc + c) * R + tr + rc * 8) = v;
  }
}

// ---- square-weight transposes (Wq,Wk,Wv,Wo x 6 layers), 6144 blocks ----
__global__ __launch_bounds__(256) void transp_sq(
    const float* __restrict__ Wq, const float* __restrict__ Wk,
    const float* __restrict__ Wv, const float* __restrict__ Wo,
    u16* __restrict__ wt) {
  int bid = blockIdx.x;
  int l = bid >> 10, z = bid & 1023;
  int m = z >> 8;
  const float* w = (m == 0) ? Wq : (m == 1) ? Wk : (m == 2) ? Wv : Wo;
  const float* src = w + (size_t)l * DD * DD;
  u16* dst = wt + (size_t)l * 12582912 + (size_t)m * DD * DD;
  int t2 = z & 255;
  transp_tile(src, dst, 1024, 1024, (t2 >> 4) * 64, (t2 & 15) * 64, threadIdx.x);
}

// ---- FFN-weight transposes (W1,W2 x 6 layers), 12288 blocks ----
__global__ __launch_bounds__(256) void transp_ffn(
    const float* __restrict__ W1, const float* __restrict__ W2,
    u16* __restrict__ wt) {
  int bid = blockIdx.x;
  int l = bid >> 11, z = bid & 2047;
  u16* base = wt + (size_t)l * 12582912;
  if (z < 1024) {
    const float* src = W1 + (size_t)l * DD * DFF;
    u16* dst = base + 4 * DD * DD;
    transp_tile(src, dst, 1024, 4096, (z >> 6) * 64, (z & 63) * 64, threadIdx.x);
  } else {
    int t2 = z - 1024;
    const float* src = W2 + (size_t)l * DFF * DD;
    u16* dst = base + 4 * DD * DD + DD * DFF;
    transp_tile(src, dst, 4096, 1024, (t2 >> 4) * 64, (t2 & 15) * 64, threadIdx.x);
  }
}

// ================= 128x128 2-phase GEMM core (proven) =================
#define STAGEAB(buf, kk0)                                                       \
  _Pragma("unroll")                                                             \
  for (int i_ = 0; i_ < 4; ++i_) {                                              \
    int g_ = i_ * 256 + tid;                                                    \
    int r_ = g_ >> 3, b_ = g_ & 7;                                              \
    int bs_ = b_ ^ (r_ & 7);                                                    \
    gload16(Ab + (size_t)r_ * K + (kk0) + bs_ * 8,                              \
            (char*)Als + (buf) * 16384 + g_ * 16);                              \
    gload16(Bb + (size_t)r_ * K + (kk0) + bs_ * 8,                              \
            (char*)Bls + (buf) * 16384 + g_ * 16);                              \
  }

#define FRAGS_MFMA(Ac, Bc)                                                      \
  _Pragma("unroll")                                                             \
  for (int kk = 0; kk < 2; ++kk) {                                              \
    bf16x8 av[4], bv[4];                                                        \
    _Pragma("unroll")                                                           \
    for (int m = 0; m < 4; ++m) {                                               \
      int r = wr + m * 16 + lr;                                                 \
      av[m] = *(const bf16x8*)((Ac) + r * 64 + (((kk * 4 + lg) ^ (r & 7)) * 8));\
    }                                                                           \
    _Pragma("unroll")                                                           \
    for (int n = 0; n < 4; ++n) {                                               \
      int r = wc + n * 16 + lr;                                                 \
      bv[n] = *(const bf16x8*)((Bc) + r * 64 + (((kk * 4 + lg) ^ (r & 7)) * 8));\
    }                                                                           \
    _Pragma("unroll")                                                           \
    for (int m = 0; m < 4; ++m)                                                 \
      _Pragma("unroll")                                                         \
      for (int n = 0; n < 4; ++n)                                               \
        acc[m][n] = __builtin_amdgcn_mfma_f32_16x16x32_bf16(av[m], bv[n],       \
                                                            acc[m][n], 0, 0, 0);\
  }

#define KLOOP(kb_, ke_)                                                         \
  STAGEAB(0, (kb_));                                                            \
  STAGEAB(1, (kb_) + 64);                                                       \
  {                                                                             \
    int cur = 0;                                                                \
    for (int k0 = (kb_); k0 < (ke_); k0 += 64) {                                \
      if (k0 + 64 < (ke_)) asm volatile("s_waitcnt vmcnt(8)" ::: "memory");     \
      else                 asm volatile("s_waitcnt vmcnt(0)" ::: "memory");     \
      __builtin_amdgcn_s_barrier();                                             \
      asm volatile("" ::: "memory");                                            \
      const u16* Ac = Als + cur * 8192;                                         \
      const u16* Bc = Bls + cur * 8192;                                         \
      FRAGS_MFMA(Ac, Bc);                                                       \
      __builtin_amdgcn_s_barrier();                                             \
      asm volatile("" ::: "memory");                                            \
      if (k0 + 128 < (ke_)) { STAGEAB(cur, k0 + 128); }                         \
      cur ^= 1;                                                                 \
    }                                                                           \
  }

// 1-D grid, XCD-pinned. VT: z==2 output written V-transposed into vtout[bh][hd][s].
template<int RELU, int BNL, int VT>
__global__ __launch_bounds__(256) void gemm_k(
    const u16* __restrict__ A,
    const u16* __restrict__ B0, const u16* __restrict__ B1, const u16* __restrict__ B2,
    const float* __restrict__ bi0, const float* __restrict__ bi1, const float* __restrict__ bi2,
    u16* __restrict__ outb, u16* __restrict__ vtout, int M, int N, int K) {
  int bid = blockIdx.x;
  int bn = bid & ((1 << BNL) - 1);
  int bm = (bid >> BNL) & 15;
  int z = bid >> (BNL + 4);
  const u16* Bt = (z == 0) ? B0 : (z == 1) ? B1 : B2;
  const float* bias = (z == 0) ? bi0 : (z == 1) ? bi1 : bi2;
  __shared__ __attribute__((aligned(16))) u16 Als[2 * 8192];
  __shared__ __attribute__((aligned(16))) u16 Bls[2 * 8192];
  int tid = threadIdx.x;
  int wave = tid >> 6, lane = tid & 63;
  int lr = lane & 15, lg = lane >> 4;
  int wr = (wave >> 1) * 64, wc = (wave & 1) * 64;
  int bm0 = bm * 128, bn0 = bn * 128;
  const u16* Ab = A + (size_t)bm0 * K;
  const u16* Bb = Bt + (size_t)bn0 * K;
  f32x4 acc[4][4] = {};
  KLOOP(0, K);
  size_t zoff = (size_t)z * M * N;
  float bb[4];
#pragma unroll
  for (int n = 0; n < 4; ++n) bb[n] = bias[bn0 + wc + n * 16 + lr];
#pragma unroll
  for (int m = 0; m < 4; ++m) {
    int row0 = bm0 + wr + m * 16 + lg * 4;
#pragma unroll
    for (int n = 0; n < 4; ++n) {
      int col = bn0 + wc + n * 16 + lr;
      if (VT && z == 2) {
        u16x4 ov;
#pragma unroll
        for (int j = 0; j < 4; ++j) ov[j] = f2bf(acc[m][n][j] + bb[n]);
        int b = row0 >> 9, s0 = row0 & 511;
        int h = col >> 6, hd = col & 63;
        *(u16x4*)(vtout + ((size_t)(((b << 4) + h) << 6) + hd) * 512 + s0) = ov;
      } else {
#pragma unroll
        for (int j = 0; j < 4; ++j) {
          float v = acc[m][n][j] + bb[n];
          if (RELU) v = fmaxf(v, 0.f);
          outb[zoff + (size_t)(row0 + j) * N + col] = f2bf(v);
        }
      }
    }
  }
}

// ---- split-K GEMM, de-atomized: each z writes its own bf16 partial buffer ----
__global__ __launch_bounds__(256) void gemm_splitp(
    const u16* __restrict__ A, const u16* __restrict__ Bt,
    u16* __restrict__ out, int M, int N, int K, int KS) {
  int bid = blockIdx.x;
  int bn = bid & 7;
  int bm = (bid >> 3) & 15;
  int zz = bid >> 7;
  __shared__ __attribute__((aligned(16))) u16 Als[2 * 8192];
  __shared__ __attribute__((aligned(16))) u16 Bls[2 * 8192];
  int tid = threadIdx.x;
  int wave = tid >> 6, lane = tid & 63;
  int lr = lane & 15, lg = lane >> 4;
  int wr = (wave >> 1) * 64, wc = (wave & 1) * 64;
  int bm0 = bm * 128, bn0 = bn * 128;
  int kb = zz * KS, ke = kb + KS;
  const u16* Ab = A + (size_t)bm0 * K;
  const u16* Bb = Bt + (size_t)bn0 * K;
  f32x4 acc[4][4] = {};
  KLOOP(kb, ke);
  u16* op = out + (size_t)zz * M * N;
#pragma unroll
  for (int m = 0; m < 4; ++m) {
    int row0 = bm0 + wr + m * 16 + lg * 4;
#pragma unroll
    for (int n = 0; n < 4; ++n) {
      int col = bn0 + wc + n * 16 + lr;
#pragma unroll
      for (int j = 0; j < 4; ++j)
        op[(size_t)(row0 + j) * N + col] = f2bf(acc[m][n][j]);
    }
  }
}

// ------- attention: one (b,h), 16 q-rows per block; 1-D XCD-pinned grid -------
__global__ __launch_bounds__(256) void attn_k(const u16* __restrict__ q,
    const u16* __restrict__ k, const u16* __restrict__ vt, u16* __restrict__ o) {
  int bid = blockIdx.x;
  int bh = ((bid & 7) << 3) | ((bid >> 3) & 7);
  int q0 = (bid >> 6) * 16;
  int b = bh >> 4, h = bh & 15;
  int tid = threadIdx.x;
  int wave = tid >> 6, lane = tid & 63;
  int lr = lane & 15, lg = lane >> 4;
  __shared__ __attribute__((aligned(16))) float sc[16 * 512];
  __shared__ __attribute__((aligned(16))) u16 Qs[16 * 64];
  __shared__ __attribute__((aligned(16))) u16 Ks[64 * 64];
  __shared__ __attribute__((aligned(16))) u16 Vs[64 * 64];
  __shared__ float red[16][17];
  __shared__ float rscale[16];
  if (tid < 128) {
    int r = tid >> 3, c = tid & 7;
    u16x8 t = *(const u16x8*)(q + (size_t)(b * SEQ + q0 + r) * DD + h * 64 + c * 8);
    *(u16x8*)(Qs + r * 64 + ((c ^ (r & 7)) * 8)) = t;
  }
  __syncthreads();
  bf16x8 qa[2];
#pragma unroll
  for (int kk = 0; kk < 2; ++kk)
    qa[kk] = *(const bf16x8*)(Qs + lr * 64 + (((kk * 4 + lg) ^ (lr & 7)) * 8));
  for (int kt = 0; kt < 8; ++kt) {
    const u16* kb0 = k + (size_t)(b * SEQ + kt * 64) * DD + h * 64;
#pragma unroll
    for (int i = 0; i < 2; ++i) {
      int g = i * 256 + tid;
      int r = g >> 3, c = g & 7;
      u16x8 t = *(const u16x8*)(kb0 + (size_t)r * DD + c * 8);
      *(u16x8*)(Ks + r * 64 + ((c ^ (r & 7)) * 8)) = t;
    }
    __syncthreads();
    f32x4 sacc = {};
#pragma unroll
    for (int kk = 0; kk < 2; ++kk) {
      int rr = wave * 16 + lr;
      bf16x8 kb = *(const bf16x8*)(Ks + rr * 64 + (((kk * 4 + lg) ^ (rr & 7)) * 8));
      sacc = __builtin_amdgcn_mfma_f32_16x16x32_bf16(qa[kk], kb, sacc, 0, 0, 0);
    }
#pragma unroll
    for (int j = 0; j < 4; ++j) {
      int row = lg * 4 + j;
      int col = kt * 64 + wave * 16 + lr;
      sc[row * 512 + (col ^ row)] = sacc[j] * 0.125f;
    }
    __syncthreads();
  }
  int r = tid & 15, ch = tid >> 4;
  float vr[32];
  float pmax = -3.0e38f;
#pragma unroll
  for (int i = 0; i < 32; ++i) {
    int c = ch * 32 + i;
    float xv = sc[r * 512 + (c ^ r)];
    vr[i] = xv;
    pmax = fmaxf(pmax, xv);
  }
  red[r][ch] = pmax;
  __syncthreads();
  float m = -3.0e38f;
#pragma unroll
  for (int i = 0; i < 16; ++i) m = fmaxf(m, red[r][i]);
  __syncthreads();
  float psum = 0.f;
#pragma unroll
  for (int i = 0; i < 32; ++i) {
    float e = __expf(vr[i] - m);
    vr[i] = e;
    psum += e;
  }
  red[r][ch] = psum;
  __syncthreads();
  float l = 0.f;
#pragma unroll
  for (int i = 0; i < 16; ++i) l += red[r][i];
  if (ch == 0) rscale[r] = 1.0f / l;
  u16* P = (u16*)sc;
#pragma unroll
  for (int i = 0; i < 32; ++i) {
    int c = ch * 32 + i;
    P[r * 512 + (((c >> 3) ^ (r & 7)) * 8) + (c & 7)] = f2bf(vr[i]);
  }
  f32x4 oacc = {};
  for (int kt = 0; kt < 8; ++kt) {
    __syncthreads();
    const u16* vb0 = vt + (size_t)bh * 64 * SEQ + kt * 64;
#pragma unroll
    for (int i = 0; i < 2; ++i) {
      int g = i * 256 + tid;
      int rr = g >> 3, c = g & 7;
      u16x8 t = *(const u16x8*)(vb0 + (size_t)rr * SEQ + c * 8);
      *(u16x8*)(Vs + rr * 64 + ((c ^ (rr & 7)) * 8)) = t;
    }
    __syncthreads();
#pragma unroll
    for (int kk = 0; kk < 2; ++kk) {
      int cb = kt * 8 + kk * 4 + lg;
      bf16x8 pa = *(const bf16x8*)(P + lr * 512 + ((cb ^ (lr & 7)) * 8));
      int rr = wave * 16 + lr;
      bf16x8 vb = *(const bf16x8*)(Vs + rr * 64 + (((kk * 4 + lg) ^ (rr & 7)) * 8));
      oacc = __builtin_amdgcn_mfma_f32_16x16x32_bf16(pa, vb, oacc, 0, 0, 0);
    }
  }
  __syncthreads();
  float* Of = sc;
#pragma unroll
  for (int j = 0; j < 4; ++j)
    Of[(lg * 4 + j) * 68 + wave * 16 + lr] = oacc[j] * rscale[lg * 4 + j];
  __syncthreads();
  {
    int rr = tid >> 4, c0 = (tid & 15) * 4;
    u16x4 ov;
#pragma unroll
    for (int j = 0; j < 4; ++j) ov[j] = f2bf(Of[rr * 68 + c0 + j]);
    *(u16x4*)(o + (size_t)(b * SEQ + q0 + rr) * DD + h * 64 + c0) = ov;
  }
}

// ---- BN stats: v = sum(4 bf16 partials) + bias + resid; materialize v; partial stats ----
__global__ __launch_bounds__(256) void bn_stats_f(const u16* __restrict__ parts,
    const float* __restrict__ bias, const float* __restrict__ resid,
    float* __restrict__ y, float* __restrict__ part) {
  int c = blockIdx.x * 256 + threadIdx.x;
  int r0 = blockIdx.y * 32;
  float b = bias[c];
  const u16* p0 = parts;
  const u16* p1 = parts + (size_t)NTOK * DD;
  const u16* p2 = parts + (size_t)2 * NTOK * DD;
  const u16* p3 = parts + (size_t)3 * NTOK * DD;
  float s = 0.f, s2 = 0.f;
  for (int r = 0; r < 32; ++r) {
    size_t idx = (size_t)(r0 + r) * DD + c;
    float v = bf2f(p0[idx]) + bf2f(p1[idx]) + bf2f(p2[idx]) + bf2f(p3[idx])
              + b + resid[idx];
    y[idx] = v;
    s += v; s2 += v * v;
  }
  size_t idx = ((size_t)blockIdx.y * DD + c) * 2;
  part[idx] = s; part[idx + 1] = s2;
}

__global__ __launch_bounds__(256) void bn_reduce_k(const float* __restrict__ part,
    const float* __restrict__ g, const float* __restrict__ be, float* __restrict__ ss) {
  int c = blockIdx.x * 256 + threadIdx.x;
  float s = 0.f, s2 = 0.f;
  for (int i = 0; i < 64; ++i) {
    s += part[((size_t)i * DD + c) * 2];
    s2 += part[((size_t)i * DD + c) * 2 + 1];
  }
  float mean = s * (1.f / 2048.f);
  float var = s2 * (1.f / 2048.f) - mean * mean;
  float rs = rsqrtf(var + 1e-3f);
  float sca = g[c] * rs;
  ss[c * 2] = sca;
  ss[c * 2 + 1] = be[c] - mean * sca;
}

// bn apply: pure scale pass over materialized v; writes xout(f32) + xb(bf16)
__global__ __launch_bounds__(256) void bn_apply_k(const float* __restrict__ y,
    const float* __restrict__ ss, float* __restrict__ xout, u16* __restrict__ xb) {
  size_t i = ((size_t)blockIdx.x * 256 + threadIdx.x) * 4;
  int c = (int)(i & (DD - 1));
  float4 v = *(const float4*)(y + i);
  float o0 = v.x * ss[c * 2] + ss[c * 2 + 1];
  float o1 = v.y * ss[(c + 1) * 2] + ss[(c + 1) * 2 + 1];
  float o2 = v.z * ss[(c + 2) * 2] + ss[(c + 2) * 2 + 1];
  float o3 = v.w * ss[(c + 3) * 2] + ss[(c + 3) * 2 + 1];
  *(float4*)(xout + i) = make_float4(o0, o1, o2, o3);
  u16x4 ob; ob[0] = f2bf(o0); ob[1] = f2bf(o1); ob[2] = f2bf(o2); ob[3] = f2bf(o3);
  *(u16x4*)(xb + i) = ob;
}

// ---------------- host ----------------
extern "C" void kernel_launch(void* const* d_in, const int* in_sizes, int n_in,
                              void* d_out, int out_size, void* d_ws, size_t ws_size,
                              hipStream_t stream) {
  const int* seq = (const int*)d_in[0];
  const float* pes = (const float*)d_in[1];
  const float* emb = (const float*)d_in[2];
  const float* Wq = (const float*)d_in[3];
  const float* bq = (const float*)d_in[4];
  const float* Wk = (const float*)d_in[5];
  const float* bk = (const float*)d_in[6];
  const float* Wv = (const float*)d_in[7];
  const float* bv = (const float*)d_in[8];
  const float* Wo = (const float*)d_in[9];
  const float* bo = (const float*)d_in[10];
  const float* W1 = (const float*)d_in[11];
  const float* b1 = (const float*)d_in[12];
  const float* W2 = (const float*)d_in[13];
  const float* b2 = (const float*)d_in[14];
  const float* g1 = (const float*)d_in[15];
  const float* be1 = (const float*)d_in[16];
  const float* g2 = (const float*)d_in[17];
  const float* be2 = (const float*)d_in[18];
  (void)in_sizes; (void)n_in; (void)out_size;

  if (ws_size < (size_t)224 * 1048576) return;

  char* ws = (char*)d_ws;
  const size_t MB = 1048576;
  u16* WT = (u16*)(ws);                      // 0..144 MB transposed bf16 weights
  float* XF = (float*)(ws + 144 * MB);       // 8 MB fp32 residual
  u16* XB = (u16*)(ws + 152 * MB);           // 4 MB bf16 x
  float* YF = (float*)(ws + 156 * MB);       // 8 MB fp32 materialized v
  u16* Qb = (u16*)(ws + 164 * MB);           // Q 164..168, K 168..172
  u16* VT = (u16*)(ws + 176 * MB);           // 4 MB
  u16* AT = (u16*)(ws + 180 * MB);           // 4 MB
  u16* HB = (u16*)(ws + 184 * MB);           // 16 MB bf16 hidden
  float* BP = (float*)(ws + 200 * MB);       // 512 KB partial stats
  float* SS = (float*)(ws + 201 * MB);       // 8 KB scale/shift
  u16* YP = (u16*)(ws + 204 * MB);           // 16 MB: 4x bf16 split-K partials

  transp_sq<<<6144, 256, 0, stream>>>(Wq, Wk, Wv, Wo, WT);
  transp_ffn<<<12288, 256, 0, stream>>>(W1, W2, WT);
  embed_k<<<NTOK, 256, 0, stream>>>(seq, pes, emb, XF, XB);
  for (int l = 0; l < 6; ++l) {
    u16* wl = WT + (size_t)l * 12582912;
    u16* wqT = wl;
    u16* wkT = wl + 1048576;
    u16* wvT = wl + 2097152;
    u16* woT = wl + 3145728;
    u16* w1T = wl + 4194304;
    u16* w2T = wl + 8388608;
    // QKV: 1-D grid 8bn x 16bm x 3z, XCD-pinned; z==2 (V) written transposed to VT
    gemm_k<0, 3, 1><<<384, 256, 0, stream>>>(XB, wqT, wkT, wvT,
        bq + l * DD, bk + l * DD, bv + l * DD, Qb, VT, NTOK, DD, DD);
    attn_k<<<2048, 256, 0, stream>>>(Qb, Qb + (size_t)NTOK * DD, VT, AT);
    // attn-out: split-K=4 bf16 partial buffers (no atomics)
    gemm_splitp<<<512, 256, 0, stream>>>(AT, woT, YP, NTOK, DD, DD, DD / 4);
    bn_stats_f<<<dim3(4, 64), 256, 0, stream>>>(YP, bo + l * DD, XF, YF, BP);
    bn_reduce_k<<<4, 256, 0, stream>>>(BP, g1 + l * DD, be1 + l * DD, SS);
    bn_apply_k<<<NTOK, 256, 0, stream>>>(YF, SS, XF, XB);
    // FFN1: 1-D grid 32bn x 16bm, XCD-pinned
    gemm_k<1, 5, 0><<<512, 256, 0, stream>>>(XB, w1T, w1T, w1T,
        b1 + l * DFF, b1 + l * DFF, b1 + l * DFF, HB, nullptr, NTOK, DFF, DD);
    // FFN2: split-K=4 bf16 partial buffers (no atomics)
    gemm_splitp<<<512, 256, 0, stream>>>(HB, w2T, YP, NTOK, DD, DFF, DFF / 4);
    bn_stats_f<<<dim3(4, 64), 256, 0, stream>>>(YP, b2 + l * DD, XF, YF, BP);
    bn_reduce_k<<<4, 256, 0, stream>>>(BP, g2 + l * DD, be2 + l * DD, SS);
    float* xfo = (l == 5) ? (float*)d_out : XF;
    bn_apply_k<<<NTOK, 256, 0, stream>>>(YF, SS, xfo, XB);
  }
}

// Round 16
// 1012.046 us; speedup vs baseline: 1.4160x; 1.0043x over previous
//
#include <hip/hip_runtime.h>
#include <hip/hip_bf16.h>
#include <cstdint>

typedef unsigned short u16;
typedef uint32_t u32;
typedef __bf16 bf16x8 __attribute__((ext_vector_type(8)));
typedef float f32x4 __attribute__((ext_vector_type(4)));
typedef u16 u16x4 __attribute__((ext_vector_type(4)));
typedef u16 u16x8 __attribute__((ext_vector_type(8)));

#define DD 1024
#define DFF 4096
#define NTOK 2048
#define SEQ 512

__device__ __forceinline__ float bf2f(u16 u) { return __uint_as_float(((u32)u) << 16); }
__device__ __forceinline__ u16 f2bf(float f) {
  __hip_bfloat16 h = __float2bfloat16(f);
  return *reinterpret_cast<u16*>(&h);
}
__device__ __forceinline__ void gload16(const void* g, void* l) {
  __builtin_amdgcn_global_load_lds((const __attribute__((address_space(1))) u32*)g,
                                   (__attribute__((address_space(3))) u32*)l, 16, 0, 0);
}

// -------- embedding + positional (f32 in, bf16 out) --------
__global__ __launch_bounds__(256) void embed_k(const int* __restrict__ seq,
    const float* __restrict__ pes, const float* __restrict__ emb,
    u16* __restrict__ xb) {
  int t = blockIdx.x;
  int s = t & (SEQ - 1);
  int tok = seq[t];
  int c = threadIdx.x * 4;
  float4 e = *(const float4*)(emb + (size_t)tok * DD + c);
  float4 p = *(const float4*)(pes + (size_t)s * DD + c);
  u16x4 ob;
  ob[0] = f2bf(e.x + p.x); ob[1] = f2bf(e.y + p.y);
  ob[2] = f2bf(e.z + p.z); ob[3] = f2bf(e.w + p.w);
  *(u16x4*)(xb + (size_t)t * DD + c) = ob;
}

// -- 64x64-tile transpose + f32->bf16: dst[C][R] = bf16(src[R][C]^T) --
__device__ __forceinline__ void transp_tile(const float* src, u16* dst, int R, int C,
                                            int tr, int tc, int tid) {
  __shared__ float tbuf[64 * 65];
#pragma unroll
  for (int i = 0; i < 4; ++i) {
    int f = i * 256 + tid;
    int r = f >> 4, c4 = (f & 15) * 4;
    float4 a = *(const float4*)(src + (size_t)(tr + r) * C + tc + c4);
    tbuf[r * 65 + c4 + 0] = a.x;
    tbuf[r * 65 + c4 + 1] = a.y;
    tbuf[r * 65 + c4 + 2] = a.z;
    tbuf[r * 65 + c4 + 3] = a.w;
  }
  __syncthreads();
#pragma unroll
  for (int i = 0; i < 2; ++i) {
    int g = i * 256 + tid;
    int c = g >> 3, rc = g & 7;
    u16x8 v;
#pragma unroll
    for (int j = 0; j < 8; ++j) v[j] = f2bf(tbuf[(rc * 8 + j) * 65 + c]);
    *(u16x8*)(dst + (size_t)(tc + c) * R + tr + rc * 8) = v;
  }
}

// ---- square-weight transposes (Wq,Wk,Wv,Wo x 6 layers), 6144 blocks ----
__global__ __launch_bounds__(256) void transp_sq(
    const float* __restrict__ Wq, const float* __restrict__ Wk,
    const float* __restrict__ Wv, const float* __restrict__ Wo,
    u16* __restrict__ wt) {
  int bid = blockIdx.x;
  int l = bid >> 10, z = bid & 1023;
  int m = z >> 8;
  const float* w = (m == 0) ? Wq : (m == 1) ? Wk : (m == 2) ? Wv : Wo;
  const float* src = w + (size_t)l * DD * DD;
  u16* dst = wt + (size_t)l * 12582912 + (size_t)m * DD * DD;
  int t2 = z & 255;
  transp_tile(src, dst, 1024, 1024, (t2 >> 4) * 64, (t2 & 15) * 64, threadIdx.x);
}

// ---- FFN-weight transposes (W1,W2 x 6 layers), 12288 blocks ----
__global__ __launch_bounds__(256) void transp_ffn(
    const float* __restrict__ W1, const float* __restrict__ W2,
    u16* __restrict__ wt) {
  int bid = blockIdx.x;
  int l = bid >> 11, z = bid & 2047;
  u16* base = wt + (size_t)l * 12582912;
  if (z < 1024) {
    const float* src = W1 + (size_t)l * DD * DFF;
    u16* dst = base + 4 * DD * DD;
    transp_tile(src, dst, 1024, 4096, (z >> 6) * 64, (z & 63) * 64, threadIdx.x);
  } else {
    int t2 = z - 1024;
    const float* src = W2 + (size_t)l * DFF * DD;
    u16* dst = base + 4 * DD * DD + DD * DFF;
    transp_tile(src, dst, 4096, 1024, (t2 >> 4) * 64, (t2 & 15) * 64, threadIdx.x);
  }
}

// ================= 128x128 2-phase GEMM core (proven) =================
#define STAGEAB(buf, kk0)                                                       \
  _Pragma("unroll")                                                             \
  for (int i_ = 0; i_ < 4; ++i_) {                                              \
    int g_ = i_ * 256 + tid;                                                    \
    int r_ = g_ >> 3, b_ = g_ & 7;                                              \
    int bs_ = b_ ^ (r_ & 7);                                                    \
    gload16(Ab + (size_t)r_ * K + (kk0) + bs_ * 8,                              \
            (char*)Als + (buf) * 16384 + g_ * 16);                              \
    gload16(Bb + (size_t)r_ * K + (kk0) + bs_ * 8,                              \
            (char*)Bls + (buf) * 16384 + g_ * 16);                              \
  }

#define FRAGS_MFMA(Ac, Bc)                                                      \
  _Pragma("unroll")                                                             \
  for (int kk = 0; kk < 2; ++kk) {                                              \
    bf16x8 av[4], bv[4];                                                        \
    _Pragma("unroll")                                                           \
    for (int m = 0; m < 4; ++m) {                                               \
      int r = wr + m * 16 + lr;                                                 \
      av[m] = *(const bf16x8*)((Ac) + r * 64 + (((kk * 4 + lg) ^ (r & 7)) * 8));\
    }                                                                           \
    _Pragma("unroll")                                                           \
    for (int n = 0; n < 4; ++n) {                                               \
      int r = wc + n * 16 + lr;                                                 \
      bv[n] = *(const bf16x8*)((Bc) + r * 64 + (((kk * 4 + lg) ^ (r & 7)) * 8));\
    }                                                                           \
    _Pragma("unroll")                                                           \
    for (int m = 0; m < 4; ++m)                                                 \
      _Pragma("unroll")                                                         \
      for (int n = 0; n < 4; ++n)                                               \
        acc[m][n] = __builtin_amdgcn_mfma_f32_16x16x32_bf16(av[m], bv[n],       \
                                                            acc[m][n], 0, 0, 0);\
  }

#define KLOOP(kb_, ke_)                                                         \
  STAGEAB(0, (kb_));                                                            \
  STAGEAB(1, (kb_) + 64);                                                       \
  {                                                                             \
    int cur = 0;                                                                \
    for (int k0 = (kb_); k0 < (ke_); k0 += 64) {                                \
      if (k0 + 64 < (ke_)) asm volatile("s_waitcnt vmcnt(8)" ::: "memory");     \
      else                 asm volatile("s_waitcnt vmcnt(0)" ::: "memory");     \
      __builtin_amdgcn_s_barrier();                                             \
      asm volatile("" ::: "memory");                                            \
      const u16* Ac = Als + cur * 8192;                                         \
      const u16* Bc = Bls + cur * 8192;                                         \
      FRAGS_MFMA(Ac, Bc);                                                       \
      __builtin_amdgcn_s_barrier();                                             \
      asm volatile("" ::: "memory");                                            \
      if (k0 + 128 < (ke_)) { STAGEAB(cur, k0 + 128); }                         \
      cur ^= 1;                                                                 \
    }                                                                           \
  }

// 1-D grid, XCD-pinned. VT: z==2 output written V-transposed into vtout[bh][hd][s].
template<int RELU, int BNL, int VT>
__global__ __launch_bounds__(256) void gemm_k(
    const u16* __restrict__ A,
    const u16* __restrict__ B0, const u16* __restrict__ B1, const u16* __restrict__ B2,
    const float* __restrict__ bi0, const float* __restrict__ bi1, const float* __restrict__ bi2,
    u16* __restrict__ outb, u16* __restrict__ vtout, int M, int N, int K) {
  int bid = blockIdx.x;
  int bn = bid & ((1 << BNL) - 1);
  int bm = (bid >> BNL) & 15;
  int z = bid >> (BNL + 4);
  const u16* Bt = (z == 0) ? B0 : (z == 1) ? B1 : B2;
  const float* bias = (z == 0) ? bi0 : (z == 1) ? bi1 : bi2;
  __shared__ __attribute__((aligned(16))) u16 Als[2 * 8192];
  __shared__ __attribute__((aligned(16))) u16 Bls[2 * 8192];
  int tid = threadIdx.x;
  int wave = tid >> 6, lane = tid & 63;
  int lr = lane & 15, lg = lane >> 4;
  int wr = (wave >> 1) * 64, wc = (wave & 1) * 64;
  int bm0 = bm * 128, bn0 = bn * 128;
  const u16* Ab = A + (size_t)bm0 * K;
  const u16* Bb = Bt + (size_t)bn0 * K;
  f32x4 acc[4][4] = {};
  KLOOP(0, K);
  size_t zoff = (size_t)z * M * N;
  float bb[4];
#pragma unroll
  for (int n = 0; n < 4; ++n) bb[n] = bias[bn0 + wc + n * 16 + lr];
#pragma unroll
  for (int m = 0; m < 4; ++m) {
    int row0 = bm0 + wr + m * 16 + lg * 4;
#pragma unroll
    for (int n = 0; n < 4; ++n) {
      int col = bn0 + wc + n * 16 + lr;
      if (VT && z == 2) {
        u16x4 ov;
#pragma unroll
        for (int j = 0; j < 4; ++j) ov[j] = f2bf(acc[m][n][j] + bb[n]);
        int b = row0 >> 9, s0 = row0 & 511;
        int h = col >> 6, hd = col & 63;
        *(u16x4*)(vtout + ((size_t)(((b << 4) + h) << 6) + hd) * 512 + s0) = ov;
      } else {
#pragma unroll
        for (int j = 0; j < 4; ++j) {
          float v = acc[m][n][j] + bb[n];
          if (RELU) v = fmaxf(v, 0.f);
          outb[zoff + (size_t)(row0 + j) * N + col] = f2bf(v);
        }
      }
    }
  }
}

// ---- split-K GEMM, de-atomized: each z writes its own bf16 partial buffer ----
__global__ __launch_bounds__(256) void gemm_splitp(
    const u16* __restrict__ A, const u16* __restrict__ Bt,
    u16* __restrict__ out, int M, int N, int K, int KS) {
  int bid = blockIdx.x;
  int bn = bid & 7;
  int bm = (bid >> 3) & 15;
  int zz = bid >> 7;
  __shared__ __attribute__((aligned(16))) u16 Als[2 * 8192];
  __shared__ __attribute__((aligned(16))) u16 Bls[2 * 8192];
  int tid = threadIdx.x;
  int wave = tid >> 6, lane = tid & 63;
  int lr = lane & 15, lg = lane >> 4;
  int wr = (wave >> 1) * 64, wc = (wave & 1) * 64;
  int bm0 = bm * 128, bn0 = bn * 128;
  int kb = zz * KS, ke = kb + KS;
  const u16* Ab = A + (size_t)bm0 * K;
  const u16* Bb = Bt + (size_t)bn0 * K;
  f32x4 acc[4][4] = {};
  KLOOP(kb, ke);
  u16* op = out + (size_t)zz * M * N;
#pragma unroll
  for (int m = 0; m < 4; ++m) {
    int row0 = bm0 + wr + m * 16 + lg * 4;
#pragma unroll
    for (int n = 0; n < 4; ++n) {
      int col = bn0 + wc + n * 16 + lr;
#pragma unroll
      for (int j = 0; j < 4; ++j)
        op[(size_t)(row0 + j) * N + col] = f2bf(acc[m][n][j]);
    }
  }
}

// ------- attention: one (b,h), 16 q-rows per block; 1-D XCD-pinned grid -------
__global__ __launch_bounds__(256) void attn_k(const u16* __restrict__ q,
    const u16* __restrict__ k, const u16* __restrict__ vt, u16* __restrict__ o) {
  int bid = blockIdx.x;
  int bh = ((bid & 7) << 3) | ((bid >> 3) & 7);
  int q0 = (bid >> 6) * 16;
  int b = bh >> 4, h = bh & 15;
  int tid = threadIdx.x;
  int wave = tid >> 6, lane = tid & 63;
  int lr = lane & 15, lg = lane >> 4;
  __shared__ __attribute__((aligned(16))) float sc[16 * 512];
  __shared__ __attribute__((aligned(16))) u16 Qs[16 * 64];
  __shared__ __attribute__((aligned(16))) u16 Ks[64 * 64];
  __shared__ __attribute__((aligned(16))) u16 Vs[64 * 64];
  __shared__ float red[16][17];
  __shared__ float rscale[16];
  if (tid < 128) {
    int r = tid >> 3, c = tid & 7;
    u16x8 t = *(const u16x8*)(q + (size_t)(b * SEQ + q0 + r) * DD + h * 64 + c * 8);
    *(u16x8*)(Qs + r * 64 + ((c ^ (r & 7)) * 8)) = t;
  }
  __syncthreads();
  bf16x8 qa[2];
#pragma unroll
  for (int kk = 0; kk < 2; ++kk)
    qa[kk] = *(const bf16x8*)(Qs + lr * 64 + (((kk * 4 + lg) ^ (lr & 7)) * 8));
  for (int kt = 0; kt < 8; ++kt) {
    const u16* kb0 = k + (size_t)(b * SEQ + kt * 64) * DD + h * 64;
#pragma unroll
    for (int i = 0; i < 2; ++i) {
      int g = i * 256 + tid;
      int r = g >> 3, c = g & 7;
      u16x8 t = *(const u16x8*)(kb0 + (size_t)r * DD + c * 8);
      *(u16x8*)(Ks + r * 64 + ((c ^ (r & 7)) * 8)) = t;
    }
    __syncthreads();
    f32x4 sacc = {};
#pragma unroll
    for (int kk = 0; kk < 2; ++kk) {
      int rr = wave * 16 + lr;
      bf16x8 kb = *(const bf16x8*)(Ks + rr * 64 + (((kk * 4 + lg) ^ (rr & 7)) * 8));
      sacc = __builtin_amdgcn_mfma_f32_16x16x32_bf16(qa[kk], kb, sacc, 0, 0, 0);
    }
#pragma unroll
    for (int j = 0; j < 4; ++j) {
      int row = lg * 4 + j;
      int col = kt * 64 + wave * 16 + lr;
      sc[row * 512 + (col ^ row)] = sacc[j] * 0.125f;
    }
    __syncthreads();
  }
  int r = tid & 15, ch = tid >> 4;
  float vr[32];
  float pmax = -3.0e38f;
#pragma unroll
  for (int i = 0; i < 32; ++i) {
    int c = ch * 32 + i;
    float xv = sc[r * 512 + (c ^ r)];
    vr[i] = xv;
    pmax = fmaxf(pmax, xv);
  }
  red[r][ch] = pmax;
  __syncthreads();
  float m = -3.0e38f;
#pragma unroll
  for (int i = 0; i < 16; ++i) m = fmaxf(m, red[r][i]);
  __syncthreads();
  float psum = 0.f;
#pragma unroll
  for (int i = 0; i < 32; ++i) {
    float e = __expf(vr[i] - m);
    vr[i] = e;
    psum += e;
  }
  red[r][ch] = psum;
  __syncthreads();
  float l = 0.f;
#pragma unroll
  for (int i = 0; i < 16; ++i) l += red[r][i];
  if (ch == 0) rscale[r] = 1.0f / l;
  u16* P = (u16*)sc;
#pragma unroll
  for (int i = 0; i < 32; ++i) {
    int c = ch * 32 + i;
    P[r * 512 + (((c >> 3) ^ (r & 7)) * 8) + (c & 7)] = f2bf(vr[i]);
  }
  f32x4 oacc = {};
  for (int kt = 0; kt < 8; ++kt) {
    __syncthreads();
    const u16* vb0 = vt + (size_t)bh * 64 * SEQ + kt * 64;
#pragma unroll
    for (int i = 0; i < 2; ++i) {
      int g = i * 256 + tid;
      int rr = g >> 3, c = g & 7;
      u16x8 t = *(const u16x8*)(vb0 + (size_t)rr * SEQ + c * 8);
      *(u16x8*)(Vs + rr * 64 + ((c ^ (rr & 7)) * 8)) = t;
    }
    __syncthreads();
#pragma unroll
    for (int kk = 0; kk < 2; ++kk) {
      int cb = kt * 8 + kk * 4 + lg;
      bf16x8 pa = *(const bf16x8*)(P + lr * 512 + ((cb ^ (lr & 7)) * 8));
      int rr = wave * 16 + lr;
      bf16x8 vb = *(const bf16x8*)(Vs + rr * 64 + (((kk * 4 + lg) ^ (rr & 7)) * 8));
      oacc = __builtin_amdgcn_mfma_f32_16x16x32_bf16(pa, vb, oacc, 0, 0, 0);
    }
  }
  __syncthreads();
  float* Of = sc;
#pragma unroll
  for (int j = 0; j < 4; ++j)
    Of[(lg * 4 + j) * 68 + wave * 16 + lr] = oacc[j] * rscale[lg * 4 + j];
  __syncthreads();
  {
    int rr = tid >> 4, c0 = (tid & 15) * 4;
    u16x4 ov;
#pragma unroll
    for (int j = 0; j < 4; ++j) ov[j] = f2bf(Of[rr * 68 + c0 + j]);
    *(u16x4*)(o + (size_t)(b * SEQ + q0 + rr) * DD + h * 64 + c0) = ov;
  }
}

// ---- BN stats: v = sum(4 bf16 partials) + bias + bf16 resid; 2 channels/thread ----
__global__ __launch_bounds__(256) void bn_stats_f(const u16* __restrict__ parts,
    const float* __restrict__ bias, const u16* __restrict__ residb,
    float* __restrict__ y, float* __restrict__ part) {
  int c2 = blockIdx.x * 256 + threadIdx.x;  // 0..511
  int c = c2 * 2;
  int r0 = blockIdx.y * 32;
  float b0 = bias[c], b1 = bias[c + 1];
  const u16* p0 = parts;
  const u16* p1 = parts + (size_t)NTOK * DD;
  const u16* p2 = parts + (size_t)2 * NTOK * DD;
  const u16* p3 = parts + (size_t)3 * NTOK * DD;
  float s0 = 0.f, s20 = 0.f, s1 = 0.f, s21 = 0.f;
  for (int r = 0; r < 32; ++r) {
    size_t idx = (size_t)(r0 + r) * DD + c;
    u32 a0 = *(const u32*)(p0 + idx);
    u32 a1 = *(const u32*)(p1 + idx);
    u32 a2 = *(const u32*)(p2 + idx);
    u32 a3 = *(const u32*)(p3 + idx);
    u32 rr = *(const u32*)(residb + idx);
    float v0 = bf2f((u16)a0) + bf2f((u16)a1) + bf2f((u16)a2) + bf2f((u16)a3)
               + b0 + bf2f((u16)rr);
    float v1 = bf2f((u16)(a0 >> 16)) + bf2f((u16)(a1 >> 16)) + bf2f((u16)(a2 >> 16))
               + bf2f((u16)(a3 >> 16)) + b1 + bf2f((u16)(rr >> 16));
    *(float2*)(y + idx) = make_float2(v0, v1);
    s0 += v0; s20 += v0 * v0;
    s1 += v1; s21 += v1 * v1;
  }
  // part layout: [rowgroup][channel][2] — float4 covers channels c, c+1
  *(f32x4*)(part + ((size_t)blockIdx.y * DD + c) * 2) = (f32x4){s0, s20, s1, s21};
}

__global__ __launch_bounds__(256) void bn_reduce_k(const float* __restrict__ part,
    const float* __restrict__ g, const float* __restrict__ be, float* __restrict__ ss) {
  int c = blockIdx.x * 256 + threadIdx.x;
  float s = 0.f, s2 = 0.f;
  for (int i = 0; i < 64; ++i) {
    s += part[((size_t)i * DD + c) * 2];
    s2 += part[((size_t)i * DD + c) * 2 + 1];
  }
  float mean = s * (1.f / 2048.f);
  float var = s2 * (1.f / 2048.f) - mean * mean;
  float rs = rsqrtf(var + 1e-3f);
  float sca = g[c] * rs;
  ss[c * 2] = sca;
  ss[c * 2 + 1] = be[c] - mean * sca;
}

// bn apply: scale pass over materialized v. LAST: write f32 d_out; else bf16 XB.
template<int LAST>
__global__ __launch_bounds__(256) void bn_apply_k(const float* __restrict__ y,
    const float* __restrict__ ss, float* __restrict__ xout, u16* __restrict__ xb) {
  size_t i = ((size_t)blockIdx.x * 256 + threadIdx.x) * 4;
  int c = (int)(i & (DD - 1));
  float4 v = *(const float4*)(y + i);
  float o0 = v.x * ss[c * 2] + ss[c * 2 + 1];
  float o1 = v.y * ss[(c + 1) * 2] + ss[(c + 1) * 2 + 1];
  float o2 = v.z * ss[(c + 2) * 2] + ss[(c + 2) * 2 + 1];
  float o3 = v.w * ss[(c + 3) * 2] + ss[(c + 3) * 2 + 1];
  if (LAST) {
    *(float4*)(xout + i) = make_float4(o0, o1, o2, o3);
  } else {
    u16x4 ob; ob[0] = f2bf(o0); ob[1] = f2bf(o1); ob[2] = f2bf(o2); ob[3] = f2bf(o3);
    *(u16x4*)(xb + i) = ob;
  }
}

// ---------------- host ----------------
extern "C" void kernel_launch(void* const* d_in, const int* in_sizes, int n_in,
                              void* d_out, int out_size, void* d_ws, size_t ws_size,
                              hipStream_t stream) {
  const int* seq = (const int*)d_in[0];
  const float* pes = (const float*)d_in[1];
  const float* emb = (const float*)d_in[2];
  const float* Wq = (const float*)d_in[3];
  const float* bq = (const float*)d_in[4];
  const float* Wk = (const float*)d_in[5];
  const float* bk = (const float*)d_in[6];
  const float* Wv = (const float*)d_in[7];
  const float* bv = (const float*)d_in[8];
  const float* Wo = (const float*)d_in[9];
  const float* bo = (const float*)d_in[10];
  const float* W1 = (const float*)d_in[11];
  const float* b1 = (const float*)d_in[12];
  const float* W2 = (const float*)d_in[13];
  const float* b2 = (const float*)d_in[14];
  const float* g1 = (const float*)d_in[15];
  const float* be1 = (const float*)d_in[16];
  const float* g2 = (const float*)d_in[17];
  const float* be2 = (const float*)d_in[18];
  (void)in_sizes; (void)n_in; (void)out_size;

  if (ws_size < (size_t)224 * 1048576) return;

  char* ws = (char*)d_ws;
  const size_t MB = 1048576;
  u16* WT = (u16*)(ws);                      // 0..144 MB transposed bf16 weights
  u16* XB = (u16*)(ws + 152 * MB);           // 4 MB bf16 x (residual stream)
  float* YF = (float*)(ws + 156 * MB);       // 8 MB fp32 materialized v
  u16* Qb = (u16*)(ws + 164 * MB);           // Q 164..168, K 168..172
  u16* VT = (u16*)(ws + 176 * MB);           // 4 MB
  u16* AT = (u16*)(ws + 180 * MB);           // 4 MB
  u16* HB = (u16*)(ws + 184 * MB);           // 16 MB bf16 hidden
  float* BP = (float*)(ws + 200 * MB);       // 512 KB partial stats
  float* SS = (float*)(ws + 201 * MB);       // 8 KB scale/shift
  u16* YP = (u16*)(ws + 204 * MB);           // 16 MB: 4x bf16 split-K partials

  transp_sq<<<6144, 256, 0, stream>>>(Wq, Wk, Wv, Wo, WT);
  transp_ffn<<<12288, 256, 0, stream>>>(W1, W2, WT);
  embed_k<<<NTOK, 256, 0, stream>>>(seq, pes, emb, XB);
  for (int l = 0; l < 6; ++l) {
    u16* wl = WT + (size_t)l * 12582912;
    u16* wqT = wl;
    u16* wkT = wl + 1048576;
    u16* wvT = wl + 2097152;
    u16* woT = wl + 3145728;
    u16* w1T = wl + 4194304;
    u16* w2T = wl + 8388608;
    // QKV: 1-D grid 8bn x 16bm x 3z, XCD-pinned; z==2 (V) written transposed to VT
    gemm_k<0, 3, 1><<<384, 256, 0, stream>>>(XB, wqT, wkT, wvT,
        bq + l * DD, bk + l * DD, bv + l * DD, Qb, VT, NTOK, DD, DD);
    attn_k<<<2048, 256, 0, stream>>>(Qb, Qb + (size_t)NTOK * DD, VT, AT);
    // attn-out: split-K=4 bf16 partial buffers (no atomics)
    gemm_splitp<<<512, 256, 0, stream>>>(AT, woT, YP, NTOK, DD, DD, DD / 4);
    bn_stats_f<<<dim3(2, 64), 256, 0, stream>>>(YP, bo + l * DD, XB, YF, BP);
    bn_reduce_k<<<4, 256, 0, stream>>>(BP, g1 + l * DD, be1 + l * DD, SS);
    bn_apply_k<0><<<NTOK, 256, 0, stream>>>(YF, SS, nullptr, XB);
    // FFN1: 1-D grid 32bn x 16bm, XCD-pinned
    gemm_k<1, 5, 0><<<512, 256, 0, stream>>>(XB, w1T, w1T, w1T,
        b1 + l * DFF, b1 + l * DFF, b1 + l * DFF, HB, nullptr, NTOK, DFF, DD);
    // FFN2: split-K=4 bf16 partial buffers (no atomics)
    gemm_splitp<<<512, 256, 0, stream>>>(HB, w2T, YP, NTOK, DD, DFF, DFF / 4);
    bn_stats_f<<<dim3(2, 64), 256, 0, stream>>>(YP, b2 + l * DD, XB, YF, BP);
    bn_reduce_k<<<4, 256, 0, stream>>>(BP, g2 + l * DD, be2 + l * DD, SS);
    if (l == 5) {
      bn_apply_k<1><<<NTOK, 256, 0, stream>>>(YF, SS, (float*)d_out, nullptr);
    } else {
      bn_apply_k<0><<<NTOK, 256, 0, stream>>>(YF, SS, nullptr, XB);
    }
  }
}